// Round 18
// baseline (165.943 us; speedup 1.0000x reference)
//
#include <hip/hip_runtime.h>
#include <math.h>

#define H 512
#define W 512
#define PLANE (H*W)       // 262144
#define PLANE4 (PLANE/4)  // 65536

typedef unsigned int uint;
typedef unsigned short ushort;
typedef _Float16 h2 __attribute__((ext_vector_type(2)));

__device__ __forceinline__ h2 bch2(uint u){ return __builtin_bit_cast(h2, u); }
__device__ __forceinline__ uint pkf16(float a, float b){
  return __builtin_bit_cast(uint, __builtin_amdgcn_cvt_pkrtz(a, b));
}

// ---- load 4x4-pixel window (2 ch-pairs per pixel) from f16 NHWC LDS tile ----
#define LOADWIN_EVEN(WIN, TL, S, YB, XB) { \
  _Pragma("unroll") for (int r_=0;r_<4;++r_){ \
    uint4 Ua = *(const uint4*)&(TL)[(((YB)+r_)*(S)+(XB))*4]; \
    uint4 Ub = *(const uint4*)&(TL)[(((YB)+r_)*(S)+(XB)+2)*4]; \
    WIN[r_][0][0]=bch2(Ua.x); WIN[r_][0][1]=bch2(Ua.y); \
    WIN[r_][1][0]=bch2(Ua.z); WIN[r_][1][1]=bch2(Ua.w); \
    WIN[r_][2][0]=bch2(Ub.x); WIN[r_][2][1]=bch2(Ub.y); \
    WIN[r_][3][0]=bch2(Ub.z); WIN[r_][3][1]=bch2(Ub.w); } }

#define LOADWIN_ODD(WIN, TL, S, YB, XB) { \
  _Pragma("unroll") for (int r_=0;r_<4;++r_){ \
    uint2 U0 = *(const uint2*)&(TL)[(((YB)+r_)*(S)+(XB))*4]; \
    uint4 U1 = *(const uint4*)&(TL)[(((YB)+r_)*(S)+(XB)+1)*4]; \
    uint2 U2 = *(const uint2*)&(TL)[(((YB)+r_)*(S)+(XB)+3)*4]; \
    WIN[r_][0][0]=bch2(U0.x); WIN[r_][0][1]=bch2(U0.y); \
    WIN[r_][1][0]=bch2(U1.x); WIN[r_][1][1]=bch2(U1.y); \
    WIN[r_][2][0]=bch2(U1.z); WIN[r_][2][1]=bch2(U1.w); \
    WIN[r_][3][0]=bch2(U2.x); WIN[r_][3][1]=bch2(U2.y); } }

// ---- bulk-prefetch a 72-uint contiguous weight group ----
#define LOADW(WL, OFF) uint WL[72]; \
  _Pragma("unroll") for (int i_=0;i_<72;++i_) WL[i_] = wpk[(OFF)+i_];

// ---- dot2 accumulate: one 4-ch group (2 pairs) x 4 co ----
#define DOTACC2(WIN, WL) { \
  _Pragma("unroll") for (int p_=0;p_<2;++p_){ \
    _Pragma("unroll") for (int dy_=0;dy_<3;++dy_){ \
      _Pragma("unroll") for (int dx_=0;dx_<3;++dx_){ \
        h2 aa=WIN[dy_][dx_][p_],   bb=WIN[dy_][dx_+1][p_]; \
        h2 cc=WIN[dy_+1][dx_][p_], dd=WIN[dy_+1][dx_+1][p_]; \
        _Pragma("unroll") for (int co_=0;co_<4;++co_){ \
          h2 wv = bch2((WL)[(co_*2+p_)*9+dy_*3+dx_]); \
          a00[co_]=__builtin_amdgcn_fdot2(aa,wv,a00[co_],false); \
          a01[co_]=__builtin_amdgcn_fdot2(bb,wv,a01[co_],false); \
          a10[co_]=__builtin_amdgcn_fdot2(cc,wv,a10[co_],false); \
          a11[co_]=__builtin_amdgcn_fdot2(dd,wv,a11[co_],false); } } } } }

// single output channel (c7), t6 half
#define DOTACC1(WIN, WL, PBASE) { \
  _Pragma("unroll") for (int p_=0;p_<2;++p_){ \
    _Pragma("unroll") for (int dy_=0;dy_<3;++dy_){ \
      _Pragma("unroll") for (int dx_=0;dx_<3;++dx_){ \
        h2 wv = bch2((WL)[((PBASE)+p_)*9+dy_*3+dx_]); \
        s00=__builtin_amdgcn_fdot2(WIN[dy_][dx_][p_],  wv,s00,false); \
        s01=__builtin_amdgcn_fdot2(WIN[dy_][dx_+1][p_],wv,s01,false); \
        s10=__builtin_amdgcn_fdot2(WIN[dy_+1][dx_][p_],  wv,s10,false); \
        s11=__builtin_amdgcn_fdot2(WIN[dy_+1][dx_+1][p_],wv,s11,false); } } } }

#define STORE_CORE(TL, S, M00, M01, M10, M11) { \
    float v00[4],v01[4],v10[4],v11[4]; \
    _Pragma("unroll") \
    for (int co_=0;co_<4;++co_){ \
      v00[co_]=(M00)?fmaxf(a00[co_],0.f):0.f; \
      v01[co_]=(M01)?fmaxf(a01[co_],0.f):0.f; \
      v10[co_]=(M10)?fmaxf(a10[co_],0.f):0.f; \
      v11[co_]=(M11)?fmaxf(a11[co_],0.f):0.f; } \
    uint4 rowlo, rowhi; \
    rowlo.x=pkf16(v00[0],v00[1]); rowlo.y=pkf16(v00[2],v00[3]); \
    rowlo.z=pkf16(v01[0],v01[1]); rowlo.w=pkf16(v01[2],v01[3]); \
    rowhi.x=pkf16(v10[0],v10[1]); rowhi.y=pkf16(v10[2],v10[3]); \
    rowhi.z=pkf16(v11[0],v11[1]); rowhi.w=pkf16(v11[2],v11[3]); \
    *(uint4*)&(TL)[(y0*(S)+x0)*4]=rowlo; \
    *(uint4*)&(TL)[((y0+1)*(S)+x0)*4]=rowhi; }

#define STORE_TILE_B(TL, S, GOFF) { \
    bool okr0=(unsigned)(gy0+(GOFF)+y0  )<512u; \
    bool okr1=(unsigned)(gy0+(GOFF)+y0+1)<512u; \
    bool okc0=(unsigned)(gx0+(GOFF)+x0  )<512u; \
    bool okc1=(unsigned)(gx0+(GOFF)+x0+1)<512u; \
    STORE_CORE(TL, S, okr0&okc0, okr0&okc1, okr1&okc0, okr1&okc1) }

// c1: scalar f16 plane -> 4 co, float weights
template<int S>
__device__ __forceinline__ void accp4sc(const ushort* __restrict__ pl,
    const float* __restrict__ w, int YB, int XB,
    float* a00, float* a01, float* a10, float* a11)
{
  float q[4][4];
  #pragma unroll
  for (int r=0;r<4;++r){
    const ushort* rp = pl + (YB+r)*S + XB;
    h2 p0 = bch2(*(const uint*)rp);
    h2 p1 = bch2(*(const uint*)(rp+2));
    q[r][0]=(float)p0.x; q[r][1]=(float)p0.y; q[r][2]=(float)p1.x; q[r][3]=(float)p1.y;
  }
  #pragma unroll
  for (int dy=0; dy<3; ++dy)
    #pragma unroll
    for (int dx=0; dx<3; ++dx){
      float q00=q[dy][dx], q01=q[dy][dx+1], q10=q[dy+1][dx], q11=q[dy+1][dx+1];
      #pragma unroll
      for (int co=0; co<4; ++co){
        float wv=w[co*9+dy*3+dx];
        a00[co]+=q00*wv; a01[co]+=q01*wv; a10[co]+=q10*wv; a11[co]+=q11*wv;
      }
    }
}

// ---------------- k_mnorm (+ block 128: weight prep + gb-acc zeroing) ----------------
__launch_bounds__(256)
__global__ void k_mnorm(const float* __restrict__ xg, const float* __restrict__ mw,
                        const float* __restrict__ mb, const float* __restrict__ ing,
                        const float* __restrict__ inb, float* __restrict__ src,
                        const float* __restrict__ c2w, const float* __restrict__ c3w,
                        const float* __restrict__ c4w, const float* __restrict__ c5w,
                        const float* __restrict__ c6w, const float* __restrict__ c7w,
                        uint* __restrict__ wpk, float* __restrict__ gbacc){
  if (blockIdx.x == 128){
    if (threadIdx.x < 16) gbacc[threadIdx.x] = 0.f;
    for (int i=threadIdx.x; i<540; i+=256){
      float f0, f1;
      if (i < 504){
        const float* sw; int CIB, rel;
        if      (i<72) { sw=c2w; CIB=0; rel=i;     int co=rel/18,p=(rel%18)/9,tap=rel%9;
                         f0=sw[(co*4+CIB+2*p)*9+tap]; f1=sw[(co*4+CIB+2*p+1)*9+tap]; }
        else if (i<144){ sw=c3w; CIB=0; rel=i-72;  int co=rel/18,p=(rel%18)/9,tap=rel%9;
                         f0=sw[(co*4+CIB+2*p)*9+tap]; f1=sw[(co*4+CIB+2*p+1)*9+tap]; }
        else if (i<216){ sw=c4w; CIB=0; rel=i-144; int co=rel/18,p=(rel%18)/9,tap=rel%9;
                         f0=sw[(co*4+CIB+2*p)*9+tap]; f1=sw[(co*4+CIB+2*p+1)*9+tap]; }
        else if (i<288){ sw=c5w; CIB=0; rel=i-216; int co=rel/18,p=(rel%18)/9,tap=rel%9;
                         f0=sw[(co*8+CIB+2*p)*9+tap]; f1=sw[(co*8+CIB+2*p+1)*9+tap]; }
        else if (i<360){ sw=c5w; CIB=4; rel=i-288; int co=rel/18,p=(rel%18)/9,tap=rel%9;
                         f0=sw[(co*8+CIB+2*p)*9+tap]; f1=sw[(co*8+CIB+2*p+1)*9+tap]; }
        else if (i<432){ sw=c6w; CIB=0; rel=i-360; int co=rel/18,p=(rel%18)/9,tap=rel%9;
                         f0=sw[(co*8+CIB+2*p)*9+tap]; f1=sw[(co*8+CIB+2*p+1)*9+tap]; }
        else           { sw=c6w; CIB=4; rel=i-432; int co=rel/18,p=(rel%18)/9,tap=rel%9;
                         f0=sw[(co*8+CIB+2*p)*9+tap]; f1=sw[(co*8+CIB+2*p+1)*9+tap]; }
      } else {
        int rel=i-504, p=rel/9, tap=rel%9;   // c7: 1 co, 4 pairs
        f0=c7w[(2*p)*9+tap]; f1=c7w[(2*p+1)*9+tap];
      }
      wpk[i] = pkf16(f0, f1);
    }
    return;
  }
  int bc = blockIdx.x;           // 128 = b*16+c
  int b = bc >> 4, c = bc & 15;
  int tid = threadIdx.x;         // 256 = out pixel (i*16+j)
  int i = tid >> 4, j = tid & 15;
  const float* xp = xg + (size_t)b*3*PLANE;
  float s = mb[c];
  #pragma unroll
  for (int dy=0; dy<3; ++dy){
    int ii = 2*i - 1 + dy;
    if ((unsigned)ii >= 32u) continue;
    #pragma unroll
    for (int dx=0; dx<3; ++dx){
      int jj = 2*j - 1 + dx;
      if ((unsigned)jj >= 32u) continue;
      int off = (ii*16)*W + jj*16;
      float vv = (xp[off] + xp[PLANE+off] + xp[2*PLANE+off]) * (1.f/3.f);
      s += vv * mw[c*9 + dy*3 + dx];
    }
  }
  float h = (s >= 0.f) ? s : 0.2f*s;
  __shared__ float red[256];
  red[tid] = h; __syncthreads();
  for (int off=128; off; off>>=1){ if (tid<off) red[tid]+=red[tid+off]; __syncthreads(); }
  float mu = red[0] * (1.f/256.f);
  __syncthreads();
  float d = h - mu;
  red[tid] = d*d; __syncthreads();
  for (int off=128; off; off>>=1){ if (tid<off) red[tid]+=red[tid+off]; __syncthreads(); }
  float var = red[0] * (1.f/256.f);
  float yv = d * rsqrtf(var + 1e-5f) * ing[c] + inb[c];
  src[(size_t)tid*128 + b*16 + c] = yv;   // src[s][b][e], s=tid
}

// ---------------- attention with inline qkv (per b,h block; head dim = 2) ----------------
__launch_bounds__(256)
__global__ void k_attn2(const float* __restrict__ src, const float* __restrict__ aw,
                        const float* __restrict__ ab, float* __restrict__ obuf){
  int b = blockIdx.x >> 3, hh = blockIdx.x & 7;  // 64 blocks
  int t = threadIdx.x;                           // token s
  __shared__ float kk0[256], kk1[256], vv0[256], vv1[256];
  int tok = t*8 + b;
  float s[16];
  #pragma unroll
  for (int e=0;e<16;++e) s[e] = src[tok*16+e];
  float q0=ab[2*hh], q1=ab[2*hh+1];
  float k0=ab[16+2*hh], k1=ab[16+2*hh+1];
  float v0=ab[32+2*hh], v1=ab[32+2*hh+1];
  #pragma unroll
  for (int e=0;e<16;++e){
    float sv=s[e];
    q0 += sv*aw[(2*hh  )*16+e]; q1 += sv*aw[(2*hh+1)*16+e];
    k0 += sv*aw[(16+2*hh)*16+e]; k1 += sv*aw[(16+2*hh+1)*16+e];
    v0 += sv*aw[(32+2*hh)*16+e]; v1 += sv*aw[(32+2*hh+1)*16+e];
  }
  kk0[t]=k0; kk1[t]=k1; vv0[t]=v0; vv1[t]=v1;
  __syncthreads();
  const float sc = 0.70710678118654752f;  // 1/sqrt(2)
  float l=0.f, a0=0.f, a1=0.f;
  for (int u=0;u<256;++u){
    float p = __expf((q0*kk0[u]+q1*kk1[u])*sc);
    l+=p; a0+=p*vv0[u]; a1+=p*vv1[u];
  }
  float inv=1.f/l;
  obuf[tok*16 + 2*hh]   = a0*inv;
  obuf[tok*16 + 2*hh+1] = a1*inv;
}

// -------- per-token: oproj+ln1 + ffn+ln2 + level partial (2048 blocks x 64 thr) --------
__launch_bounds__(64)
__global__ void k_tok(const float* __restrict__ src, const float* __restrict__ obuf,
                      const float* __restrict__ ow, const float* __restrict__ ob,
                      const float* __restrict__ l1w, const float* __restrict__ l1b,
                      const float* __restrict__ l2w, const float* __restrict__ l2b,
                      const float* __restrict__ n1g, const float* __restrict__ n1b,
                      const float* __restrict__ n2g, const float* __restrict__ n2b,
                      const float* __restrict__ fw, float* __restrict__ gbacc){
  int tok = blockIdx.x, tid = threadIdx.x;
  int s = tok >> 3, b = tok & 7;
  __shared__ float shx[16], shy[16], h1[128];
  if (tid < 16){
    float t2 = ob[tid];
    #pragma unroll
    for (int f=0;f<16;++f) t2 += obuf[tok*16+f]*ow[tid*16+f];
    shx[tid] = src[tok*16+tid] + t2;
  }
  __syncthreads();
  if (tid < 16){
    float mu=0.f;
    #pragma unroll
    for (int e=0;e<16;++e) mu+=shx[e];
    mu*=(1.f/16.f);
    float var=0.f;
    #pragma unroll
    for (int e=0;e<16;++e){ float d=shx[e]-mu; var+=d*d; }
    var*=(1.f/16.f);
    shy[tid] = (shx[tid]-mu)*rsqrtf(var+1e-5f)*n1g[tid]+n1b[tid];
  }
  __syncthreads();
  for (int i=tid;i<128;i+=64){
    float u=l1b[i];
    #pragma unroll
    for (int e=0;e<16;++e) u += shy[e]*l1w[i*16+e];
    h1[i]=fmaxf(u,0.f);
  }
  __syncthreads();
  if (tid < 16){
    float x2=l2b[tid];
    for (int jj=0;jj<128;++jj) x2 += h1[jj]*l2w[tid*128+jj];
    shx[tid] = x2 + shy[tid];
  }
  __syncthreads();
  if (tid < 16){
    float mu=0.f;
    #pragma unroll
    for (int e=0;e<16;++e) mu+=shx[e];
    mu*=(1.f/16.f);
    float var=0.f;
    #pragma unroll
    for (int e=0;e<16;++e){ float d=shx[e]-mu; var+=d*d; }
    var*=(1.f/16.f);
    shy[tid]=(shx[tid]-mu)*rsqrtf(var+1e-5f)*n2g[tid]+n2b[tid];
  }
  __syncthreads();
  if (tid < 2){
    float p=0.f;
    #pragma unroll
    for (int c=0;c<16;++c) p += shy[c]*fw[(tid*16+c)*256 + s];
    atomicAdd(&gbacc[b*2+tid], p);
  }
}

// ---- c7 helpers: recompute x1 rows from vb (register rotation) ----
// load 6 cols of vb row (y0+5+RR), cols x0+5..x0+10
#define LOADVB(DST, RR) { \
  _Pragma("unroll") for (int c_=0;c_<6;++c_) \
    DST[c_] = (float)(*(const _Float16*)&vbp[((y0+5+(RR)))*46 + x0+5+c_]); }

// x1 row RBASE (4 px x 4 ch) from 3 vb rows
#define X1R(DST, R0, R1, R2, RBASE) { \
  _Pragma("unroll") for (int c_=0;c_<4;++c_){ \
    bool ok_ = interior || (((unsigned)(gy0+y0-1+(RBASE))<512u)&((unsigned)(gx0+x0-1+c_)<512u)); \
    _Pragma("unroll") for (int co_=0;co_<4;++co_){ \
      float a_=c1b[co_]; \
      _Pragma("unroll") for (int dx_=0;dx_<3;++dx_){ \
        a_ += R0[c_+dx_]*c1w[co_*9+dx_]; \
        a_ += R1[c_+dx_]*c1w[co_*9+3+dx_]; \
        a_ += R2[c_+dx_]*c1w[co_*9+6+dx_]; } \
      DST[c_][co_] = ok_?fmaxf(a_,0.f):0.f; } } }

// c7 slice dy=DYI with x1 rows RL (row DYI) and RH (row DYI+1)
#define SL7(RL, RH, DYI) { \
  _Pragma("unroll") for (int dx_=0;dx_<3;++dx_){ \
    _Pragma("unroll") for (int co_=0;co_<4;++co_){ \
      float w_=c7w[co_*9+(DYI)*3+dx_]; \
      s00 += RL[dx_][co_]*w_;   s01 += RL[dx_+1][co_]*w_; \
      s10 += RH[dx_][co_]*w_;   s11 += RH[dx_+1][co_]*w_; } } }

// ============ fused conv chain + final elementwise ============
// Aliased LDS arena = 53072 B -> 3 WG/CU. t1 recompute for c7 (from vb).
// launch_bounds arg-2 acts as min BLOCKS/CU: VGPR cap at (512,3) ~85; current use ~70.
__launch_bounds__(512,3)
__global__ void k_megaconv(const float* __restrict__ xg,
    const float* __restrict__ c1w, const float* __restrict__ c1b,
    const float* __restrict__ c2b, const float* __restrict__ c3b,
    const float* __restrict__ c4b, const float* __restrict__ c5b,
    const float* __restrict__ c6b, const float* __restrict__ c7b,
    const float* __restrict__ c7w,
    const uint* __restrict__ wpk, const float* __restrict__ gbr,
    const float* __restrict__ fb,
    float* __restrict__ out)
{
  // arena offsets (ushorts, all uint4-aligned):
  // vb@0 (2116, pad->2120) | t2@2120 (7056) | t3@9176 (6400) | t4@15576 (5776) | t5@21352 (5184)
  // t6 alias t3@9176 (4624) | t1 alias t4..t5@15576 (7744). total 26536 ushorts = 53072 B
  __shared__ __align__(16) ushort arena[26536];
  ushort* vbp = arena;
  ushort* t2  = arena + 2120;
  ushort* t3  = arena + 9176;
  ushort* t4  = arena + 15576;
  ushort* t5  = arena + 21352;
  ushort* t6  = arena + 9176;    // alias t3 (t3 dead after c5)
  ushort* t1  = arena + 15576;   // alias t4+t5 (t1 dead before c4)
  int wg=blockIdx.x, b=wg>>8, t=wg&255, ty=t>>4, tx=t&15;
  int gy0=ty*32, gx0=tx*32, tid=threadIdx.x;
  const float* xp = xg + (size_t)b*3*PLANE;
  const bool interior = (ty>=1)&(ty<=14)&(tx>=1)&(tx<=14);

  // stage v window (origin gy0-7, gx0-7), 46x46, f16
  if (interior){
    for (int i=tid;i<46*46;i+=512){
      int rr=i/46, cc=i-rr*46;
      int off=(gy0-7+rr)*W + gx0-7+cc;
      float val=(xp[off]+xp[PLANE+off]+xp[2*PLANE+off])*(1.f/3.f);
      _Float16 hv=(_Float16)val;
      vbp[i]=*(ushort*)&hv;
    }
  } else {
    for (int i=tid;i<46*46;i+=512){
      int rr=i/46, cc=i-rr*46;
      int gy=gy0-7+rr, gx=gx0-7+cc;
      float val=0.f;
      if (((unsigned)gy<512u)&((unsigned)gx<512u)){
        int off=gy*W+gx;
        val=(xp[off]+xp[PLANE+off]+xp[2*PLANE+off])*(1.f/3.f);
      }
      _Float16 hv=(_Float16)val;
      vbp[i]=*(ushort*)&hv;
    }
  }
  __syncthreads();

  // c1: vb(46) -> t1(44), out origin gy0-6
  if (tid < 484){
    int qy=tid/22, qx=tid-qy*22, y0=2*qy, x0=2*qx;
    float a00[4],a01[4],a10[4],a11[4];
    #pragma unroll
    for (int co=0;co<4;++co){ float bv=c1b[co]; a00[co]=bv;a01[co]=bv;a10[co]=bv;a11[co]=bv; }
    accp4sc<46>(vbp, c1w, y0, x0, a00,a01,a10,a11);
    if (interior){ STORE_CORE(t1, 44, true, true, true, true) }
    else         { STORE_TILE_B(t1, 44, -6) }
  }
  __syncthreads();

  // c2: t1(44) -> t2(42), out origin gy0-5
  if (tid < 441){
    int qy=tid/21, qx=tid-qy*21, y0=2*qy, x0=2*qx;
    float a00[4],a01[4],a10[4],a11[4];
    #pragma unroll
    for (int co=0;co<4;++co){ float bv=c2b[co]; a00[co]=bv;a01[co]=bv;a10[co]=bv;a11[co]=bv; }
    h2 win[4][4][2];
    LOADWIN_EVEN(win, t1, 44, y0, x0)
    LOADW(wl2, 0)
    DOTACC2(win, wl2)
    if (interior){ STORE_CORE(t2, 42, true, true, true, true) }
    else         { STORE_TILE_B(t2, 42, -5) }
  }
  __syncthreads();

  // c3: t2(42) -> t3(40), out origin gy0-4
  if (tid < 400){
    int qy=tid/20, qx=tid-qy*20, y0=2*qy, x0=2*qx;
    float a00[4],a01[4],a10[4],a11[4];
    #pragma unroll
    for (int co=0;co<4;++co){ float bv=c3b[co]; a00[co]=bv;a01[co]=bv;a10[co]=bv;a11[co]=bv; }
    h2 win[4][4][2];
    LOADWIN_EVEN(win, t2, 42, y0, x0)
    LOADW(wl3, 72)
    DOTACC2(win, wl3)
    if (interior){ STORE_CORE(t3, 40, true, true, true, true) }
    else         { STORE_TILE_B(t3, 40, -4) }
  }
  __syncthreads();

  // c4: t3(40) -> t4(38), out origin gy0-3   (overwrites t1 region; t1 dead)
  if (tid < 361){
    int qy=tid/19, qx=tid-qy*19, y0=2*qy, x0=2*qx;
    float a00[4],a01[4],a10[4],a11[4];
    #pragma unroll
    for (int co=0;co<4;++co){ float bv=c4b[co]; a00[co]=bv;a01[co]=bv;a10[co]=bv;a11[co]=bv; }
    h2 win[4][4][2];
    LOADWIN_EVEN(win, t3, 40, y0, x0)
    LOADW(wl4, 144)
    DOTACC2(win, wl4)
    if (interior){ STORE_CORE(t4, 38, true, true, true, true) }
    else         { STORE_TILE_B(t4, 38, -3) }
  }
  __syncthreads();

  // c5: concat(t3@(+1,+1) odd, t4) -> t5(36), out origin gy0-2
  if (tid < 324){
    int qy=tid/18, qx=tid-qy*18, y0=2*qy, x0=2*qx;
    float a00[4],a01[4],a10[4],a11[4];
    #pragma unroll
    for (int co=0;co<4;++co){ float bv=c5b[co]; a00[co]=bv;a01[co]=bv;a10[co]=bv;a11[co]=bv; }
    {
      h2 win[4][4][2];
      LOADWIN_ODD(win, t3, 40, y0+1, x0+1)
      LOADW(wlA, 216)
      DOTACC2(win, wlA)
    }
    {
      h2 win[4][4][2];
      LOADWIN_EVEN(win, t4, 38, y0, x0)
      LOADW(wlB, 288)
      DOTACC2(win, wlB)
    }
    if (interior){ STORE_CORE(t5, 36, true, true, true, true) }
    else         { STORE_TILE_B(t5, 36, -2) }
  }
  __syncthreads();

  // c6: concat(t2@(+3,+3) odd, t5) -> t6(34), out origin gy0-1  (t6 aliases t3; t3 dead)
  if (tid < 289){
    int qy=tid/17, qx=tid-qy*17, y0=2*qy, x0=2*qx;
    float a00[4],a01[4],a10[4],a11[4];
    #pragma unroll
    for (int co=0;co<4;++co){ float bv=c6b[co]; a00[co]=bv;a01[co]=bv;a10[co]=bv;a11[co]=bv; }
    {
      h2 win[4][4][2];
      LOADWIN_ODD(win, t2, 42, y0+3, x0+3)
      LOADW(wlA, 360)
      DOTACC2(win, wlA)
    }
    {
      h2 win[4][4][2];
      LOADWIN_EVEN(win, t5, 36, y0, x0)
      LOADW(wlB, 432)
      DOTACC2(win, wlB)
    }
    if (interior){ STORE_CORE(t6, 34, true, true, true, true) }
    else         { STORE_TILE_B(t6, 34, -1) }
  }
  __syncthreads();

  // c7: concat(x1 recomputed from vb, t6) -> sigmoid -> v_r + fused final elementwise
  if (tid < 256){
    int qy=tid>>4, qx=tid&15, y0=2*qy, x0=2*qx;
    float bv=c7b[0];
    float s00=bv, s01=bv, s10=bv, s11=bv;
    // t6 half via packed dot2
    uint wl7[36];
    #pragma unroll
    for (int i_=0;i_<36;++i_) wl7[i_]=wpk[504+i_];
    {
      h2 win[4][4][2];
      LOADWIN_EVEN(win, t6, 34, y0, x0)
      DOTACC1(win, wl7, 2)
    }
    // x1 half recomputed from vb with row rotation
    {
      float va[6], vb_[6], vc[6], vd[6];
      float xr0[4][4], xr1[4][4];
      LOADVB(va,0) LOADVB(vb_,1) LOADVB(vc,2)
      X1R(xr0, va, vb_, vc, 0)
      LOADVB(vd,3)
      X1R(xr1, vb_, vc, vd, 1)
      SL7(xr0, xr1, 0)
      LOADVB(va,4)
      X1R(xr0, vc, vd, va, 2)
      SL7(xr1, xr0, 1)
      LOADVB(vb_,5)
      X1R(xr1, vd, va, vb_, 3)
      SL7(xr0, xr1, 2)
    }
    s00 = 1.f/(1.f+__expf(-s00)); s01 = 1.f/(1.f+__expf(-s01));
    s10 = 1.f/(1.f+__expf(-s10)); s11 = 1.f/(1.f+__expf(-s11));
    float* vo = out + 6291456 + (size_t)b*PLANE;
    *(float2*)&vo[(gy0+y0  )*512 + gx0+x0] = make_float2(s00,s01);
    *(float2*)&vo[(gy0+y0+1)*512 + gx0+x0] = make_float2(s10,s11);

    // level scalars from raw accumulated sums
    float lev0 = 1.f/(1.f+__expf(-(gbr[b*2+0]+fb[0])));
    float lev1 = 1.f/(1.f+__expf(-(gbr[b*2+1]+fb[1])));
    float gg  = 0.1f*lev0+0.2f;
    float bcf = 0.04f*lev1+0.06f;
    float lg = log2f(gg);
    #pragma unroll
    for (int py=0; py<2; ++py){
      int gy=gy0+y0+py, gx=gx0+x0;
      int off=gy*W+gx;
      float2 R = *(const float2*)&xp[off];
      float2 G = *(const float2*)&xp[PLANE+off];
      float2 B = *(const float2*)&xp[2*PLANE+off];
      float vr0 = py? s10:s00, vr1 = py? s11:s01;
      float2 er,eg,eb,tr,tg,tb;
#define COMP1(RF,GF,BF,VRF,ER,EG,EB,TR,TG,TB) { \
      float vv=(RF+GF+BF)*(1.f/3.f); \
      float v0c=fminf(fmaxf(vv,1e-6f),0.999999f); \
      float r0=exp2f((VRF)*lg); \
      float ev0=exp2f(r0*log2f(v0c)); \
      float dd=bcf-vv; \
      float L=400.f*dd*dd*dd; \
      L=(L<1e-5f)?1e-6f:L; \
      float fac=(ev0-L)/(vv+1e-6f); \
      ER=RF*fac; EG=GF*fac; EB=BF*fac; \
      bool z=vv>0.04f; \
      TR=z?0.f:ER; TG=z?0.f:EG; TB=z?0.f:EB; }
      COMP1(R.x,G.x,B.x,vr0, er.x,eg.x,eb.x, tr.x,tg.x,tb.x)
      COMP1(R.y,G.y,B.y,vr1, er.y,eg.y,eb.y, tr.y,tg.y,tb.y)
#undef COMP1
      *(float2*)&out[(size_t)(b*3+0)*PLANE + off] = er;
      *(float2*)&out[(size_t)(b*3+1)*PLANE + off] = eg;
      *(float2*)&out[(size_t)(b*3+2)*PLANE + off] = eb;
      *(float2*)&out[8388608 + (size_t)(b*3+0)*PLANE + off] = tr;
      *(float2*)&out[8388608 + (size_t)(b*3+1)*PLANE + off] = tg;
      *(float2*)&out[8388608 + (size_t)(b*3+2)*PLANE + off] = tb;
    }
  }
}

extern "C" void kernel_launch(void* const* d_in, const int* in_sizes, int n_in,
                              void* d_out, int out_size, void* d_ws, size_t ws_size,
                              hipStream_t stream) {
  const float* x    = (const float*)d_in[0];
  const float* c1w  = (const float*)d_in[1];  const float* c1b = (const float*)d_in[2];
  const float* c2w  = (const float*)d_in[3];  const float* c2b = (const float*)d_in[4];
  const float* c3w  = (const float*)d_in[5];  const float* c3b = (const float*)d_in[6];
  const float* c4w  = (const float*)d_in[7];  const float* c4b = (const float*)d_in[8];
  const float* c5w  = (const float*)d_in[9];  const float* c5b = (const float*)d_in[10];
  const float* c6w  = (const float*)d_in[11]; const float* c6b = (const float*)d_in[12];
  const float* c7w  = (const float*)d_in[13]; const float* c7b = (const float*)d_in[14];
  const float* mw   = (const float*)d_in[15]; const float* mb  = (const float*)d_in[16];
  const float* ing  = (const float*)d_in[17]; const float* inb = (const float*)d_in[18];
  const float* aw   = (const float*)d_in[19]; const float* ab  = (const float*)d_in[20];
  const float* ow   = (const float*)d_in[21]; const float* ob  = (const float*)d_in[22];
  const float* l1w  = (const float*)d_in[23]; const float* l1b = (const float*)d_in[24];
  const float* l2w  = (const float*)d_in[25]; const float* l2b = (const float*)d_in[26];
  const float* n1g  = (const float*)d_in[27]; const float* n1b = (const float*)d_in[28];
  const float* n2g  = (const float*)d_in[29]; const float* n2b = (const float*)d_in[30];
  const float* fw   = (const float*)d_in[31]; const float* fb  = (const float*)d_in[32];

  uint* wpk = (uint*)d_ws;             // 540 uints
  float* gbacc = (float*)(wpk + 1024); // 16 floats (raw level sums)
  float* src  = gbacc + 16;            // 32,768
  float* obuf = src + 32768;           // 32,768
  float* out  = (float*)d_out;

  k_mnorm<<<129,256,0,stream>>>(x, mw, mb, ing, inb, src,
                                c2w, c3w, c4w, c5w, c6w, c7w, wpk, gbacc);
  k_attn2<<<64,256,0,stream>>>(src, aw, ab, obuf);
  k_tok<<<2048,64,0,stream>>>(src, obuf, ow, ob, l1w, l1b, l2w, l2b,
                              n1g, n1b, n2g, n2b, fw, gbacc);
  k_megaconv<<<2048,512,0,stream>>>(x, c1w, c1b, c2b, c3b, c4b, c5b, c6b, c7b,
                                    c7w, wpk, gbacc, fb, out);
}

// Round 19
// 153.637 us; speedup vs baseline: 1.0801x; 1.0801x over previous
//
#include <hip/hip_runtime.h>
#include <math.h>

#define H 512
#define W 512
#define PLANE (H*W)       // 262144
#define PLANE4 (PLANE/4)  // 65536

typedef unsigned int uint;
typedef unsigned short ushort;
typedef _Float16 h2 __attribute__((ext_vector_type(2)));

__device__ __forceinline__ h2 bch2(uint u){ return __builtin_bit_cast(h2, u); }
__device__ __forceinline__ uint pkf16(float a, float b){
  return __builtin_bit_cast(uint, __builtin_amdgcn_cvt_pkrtz(a, b));
}

// ---- load 4x4-pixel window (2 ch-pairs per pixel) from f16 NHWC LDS tile ----
#define LOADWIN_EVEN(WIN, TL, S, YB, XB) { \
  _Pragma("unroll") for (int r_=0;r_<4;++r_){ \
    uint4 Ua = *(const uint4*)&(TL)[(((YB)+r_)*(S)+(XB))*4]; \
    uint4 Ub = *(const uint4*)&(TL)[(((YB)+r_)*(S)+(XB)+2)*4]; \
    WIN[r_][0][0]=bch2(Ua.x); WIN[r_][0][1]=bch2(Ua.y); \
    WIN[r_][1][0]=bch2(Ua.z); WIN[r_][1][1]=bch2(Ua.w); \
    WIN[r_][2][0]=bch2(Ub.x); WIN[r_][2][1]=bch2(Ub.y); \
    WIN[r_][3][0]=bch2(Ub.z); WIN[r_][3][1]=bch2(Ub.w); } }

#define LOADWIN_ODD(WIN, TL, S, YB, XB) { \
  _Pragma("unroll") for (int r_=0;r_<4;++r_){ \
    uint2 U0 = *(const uint2*)&(TL)[(((YB)+r_)*(S)+(XB))*4]; \
    uint4 U1 = *(const uint4*)&(TL)[(((YB)+r_)*(S)+(XB)+1)*4]; \
    uint2 U2 = *(const uint2*)&(TL)[(((YB)+r_)*(S)+(XB)+3)*4]; \
    WIN[r_][0][0]=bch2(U0.x); WIN[r_][0][1]=bch2(U0.y); \
    WIN[r_][1][0]=bch2(U1.x); WIN[r_][1][1]=bch2(U1.y); \
    WIN[r_][2][0]=bch2(U1.z); WIN[r_][2][1]=bch2(U1.w); \
    WIN[r_][3][0]=bch2(U2.x); WIN[r_][3][1]=bch2(U2.y); } }

// ---- bulk-prefetch a 72-uint contiguous weight group ----
#define LOADW(WL, OFF) uint WL[72]; \
  _Pragma("unroll") for (int i_=0;i_<72;++i_) WL[i_] = wpk[(OFF)+i_];

// ---- dot2 accumulate: one 4-ch group (2 pairs) x 4 co ----
#define DOTACC2(WIN, WL) { \
  _Pragma("unroll") for (int p_=0;p_<2;++p_){ \
    _Pragma("unroll") for (int dy_=0;dy_<3;++dy_){ \
      _Pragma("unroll") for (int dx_=0;dx_<3;++dx_){ \
        h2 aa=WIN[dy_][dx_][p_],   bb=WIN[dy_][dx_+1][p_]; \
        h2 cc=WIN[dy_+1][dx_][p_], dd=WIN[dy_+1][dx_+1][p_]; \
        _Pragma("unroll") for (int co_=0;co_<4;++co_){ \
          h2 wv = bch2((WL)[(co_*2+p_)*9+dy_*3+dx_]); \
          a00[co_]=__builtin_amdgcn_fdot2(aa,wv,a00[co_],false); \
          a01[co_]=__builtin_amdgcn_fdot2(bb,wv,a01[co_],false); \
          a10[co_]=__builtin_amdgcn_fdot2(cc,wv,a10[co_],false); \
          a11[co_]=__builtin_amdgcn_fdot2(dd,wv,a11[co_],false); } } } } }

// single output channel (c7)
#define DOTACC1(WIN, WL, PBASE) { \
  _Pragma("unroll") for (int p_=0;p_<2;++p_){ \
    _Pragma("unroll") for (int dy_=0;dy_<3;++dy_){ \
      _Pragma("unroll") for (int dx_=0;dx_<3;++dx_){ \
        h2 wv = bch2((WL)[((PBASE)+p_)*9+dy_*3+dx_]); \
        s00=__builtin_amdgcn_fdot2(WIN[dy_][dx_][p_],  wv,s00,false); \
        s01=__builtin_amdgcn_fdot2(WIN[dy_][dx_+1][p_],wv,s01,false); \
        s10=__builtin_amdgcn_fdot2(WIN[dy_+1][dx_][p_],  wv,s10,false); \
        s11=__builtin_amdgcn_fdot2(WIN[dy_+1][dx_+1][p_],wv,s11,false); } } } }

#define STORE_CORE(TL, S, M00, M01, M10, M11) { \
    float v00[4],v01[4],v10[4],v11[4]; \
    _Pragma("unroll") \
    for (int co_=0;co_<4;++co_){ \
      v00[co_]=(M00)?fmaxf(a00[co_],0.f):0.f; \
      v01[co_]=(M01)?fmaxf(a01[co_],0.f):0.f; \
      v10[co_]=(M10)?fmaxf(a10[co_],0.f):0.f; \
      v11[co_]=(M11)?fmaxf(a11[co_],0.f):0.f; } \
    uint4 rowlo, rowhi; \
    rowlo.x=pkf16(v00[0],v00[1]); rowlo.y=pkf16(v00[2],v00[3]); \
    rowlo.z=pkf16(v01[0],v01[1]); rowlo.w=pkf16(v01[2],v01[3]); \
    rowhi.x=pkf16(v10[0],v10[1]); rowhi.y=pkf16(v10[2],v10[3]); \
    rowhi.z=pkf16(v11[0],v11[1]); rowhi.w=pkf16(v11[2],v11[3]); \
    *(uint4*)&(TL)[(y0*(S)+x0)*4]=rowlo; \
    *(uint4*)&(TL)[((y0+1)*(S)+x0)*4]=rowhi; }

#define STORE_TILE_B(TL, S, GOFF) { \
    bool okr0=(unsigned)(gy0+(GOFF)+y0  )<512u; \
    bool okr1=(unsigned)(gy0+(GOFF)+y0+1)<512u; \
    bool okc0=(unsigned)(gx0+(GOFF)+x0  )<512u; \
    bool okc1=(unsigned)(gx0+(GOFF)+x0+1)<512u; \
    STORE_CORE(TL, S, okr0&okc0, okr0&okc1, okr1&okc0, okr1&okc1) }

// c1: scalar f16 plane -> 4 co, float weights
template<int S>
__device__ __forceinline__ void accp4sc(const ushort* __restrict__ pl,
    const float* __restrict__ w, int YB, int XB,
    float* a00, float* a01, float* a10, float* a11)
{
  float q[4][4];
  #pragma unroll
  for (int r=0;r<4;++r){
    const ushort* rp = pl + (YB+r)*S + XB;
    h2 p0 = bch2(*(const uint*)rp);
    h2 p1 = bch2(*(const uint*)(rp+2));
    q[r][0]=(float)p0.x; q[r][1]=(float)p0.y; q[r][2]=(float)p1.x; q[r][3]=(float)p1.y;
  }
  #pragma unroll
  for (int dy=0; dy<3; ++dy)
    #pragma unroll
    for (int dx=0; dx<3; ++dx){
      float q00=q[dy][dx], q01=q[dy][dx+1], q10=q[dy+1][dx], q11=q[dy+1][dx+1];
      #pragma unroll
      for (int co=0; co<4; ++co){
        float wv=w[co*9+dy*3+dx];
        a00[co]+=q00*wv; a01[co]+=q01*wv; a10[co]+=q10*wv; a11[co]+=q11*wv;
      }
    }
}

// ---------------- k_mnorm (+ block 128: weight prep + gb-acc zeroing) ----------------
// wpk groups (72 each, contiguous): c2@0 c3@72 c4@144 c5g0@216 c5g1@288 c6g0@360 c6g1@432 c7@504(36)
__launch_bounds__(256)
__global__ void k_mnorm(const float* __restrict__ xg, const float* __restrict__ mw,
                        const float* __restrict__ mb, const float* __restrict__ ing,
                        const float* __restrict__ inb, float* __restrict__ src,
                        const float* __restrict__ c2w, const float* __restrict__ c3w,
                        const float* __restrict__ c4w, const float* __restrict__ c5w,
                        const float* __restrict__ c6w, const float* __restrict__ c7w,
                        uint* __restrict__ wpk, float* __restrict__ gbacc){
  if (blockIdx.x == 128){
    if (threadIdx.x < 16) gbacc[threadIdx.x] = 0.f;
    for (int i=threadIdx.x; i<540; i+=256){
      float f0, f1;
      if (i < 504){
        const float* sw; int CIB, rel;
        if      (i<72) { sw=c2w; CIB=0; rel=i;     int co=rel/18,p=(rel%18)/9,tap=rel%9;
                         f0=sw[(co*4+CIB+2*p)*9+tap]; f1=sw[(co*4+CIB+2*p+1)*9+tap]; }
        else if (i<144){ sw=c3w; CIB=0; rel=i-72;  int co=rel/18,p=(rel%18)/9,tap=rel%9;
                         f0=sw[(co*4+CIB+2*p)*9+tap]; f1=sw[(co*4+CIB+2*p+1)*9+tap]; }
        else if (i<216){ sw=c4w; CIB=0; rel=i-144; int co=rel/18,p=(rel%18)/9,tap=rel%9;
                         f0=sw[(co*4+CIB+2*p)*9+tap]; f1=sw[(co*4+CIB+2*p+1)*9+tap]; }
        else if (i<288){ sw=c5w; CIB=0; rel=i-216; int co=rel/18,p=(rel%18)/9,tap=rel%9;
                         f0=sw[(co*8+CIB+2*p)*9+tap]; f1=sw[(co*8+CIB+2*p+1)*9+tap]; }
        else if (i<360){ sw=c5w; CIB=4; rel=i-288; int co=rel/18,p=(rel%18)/9,tap=rel%9;
                         f0=sw[(co*8+CIB+2*p)*9+tap]; f1=sw[(co*8+CIB+2*p+1)*9+tap]; }
        else if (i<432){ sw=c6w; CIB=0; rel=i-360; int co=rel/18,p=(rel%18)/9,tap=rel%9;
                         f0=sw[(co*8+CIB+2*p)*9+tap]; f1=sw[(co*8+CIB+2*p+1)*9+tap]; }
        else           { sw=c6w; CIB=4; rel=i-432; int co=rel/18,p=(rel%18)/9,tap=rel%9;
                         f0=sw[(co*8+CIB+2*p)*9+tap]; f1=sw[(co*8+CIB+2*p+1)*9+tap]; }
      } else {
        int rel=i-504, p=rel/9, tap=rel%9;   // c7: 1 co, 4 pairs
        f0=c7w[(2*p)*9+tap]; f1=c7w[(2*p+1)*9+tap];
      }
      wpk[i] = pkf16(f0, f1);
    }
    return;
  }
  int bc = blockIdx.x;           // 128 = b*16+c
  int b = bc >> 4, c = bc & 15;
  int tid = threadIdx.x;         // 256 = out pixel (i*16+j)
  int i = tid >> 4, j = tid & 15;
  const float* xp = xg + (size_t)b*3*PLANE;
  float s = mb[c];
  #pragma unroll
  for (int dy=0; dy<3; ++dy){
    int ii = 2*i - 1 + dy;
    if ((unsigned)ii >= 32u) continue;
    #pragma unroll
    for (int dx=0; dx<3; ++dx){
      int jj = 2*j - 1 + dx;
      if ((unsigned)jj >= 32u) continue;
      int off = (ii*16)*W + jj*16;
      float vv = (xp[off] + xp[PLANE+off] + xp[2*PLANE+off]) * (1.f/3.f);
      s += vv * mw[c*9 + dy*3 + dx];
    }
  }
  float h = (s >= 0.f) ? s : 0.2f*s;
  __shared__ float red[256];
  red[tid] = h; __syncthreads();
  for (int off=128; off; off>>=1){ if (tid<off) red[tid]+=red[tid+off]; __syncthreads(); }
  float mu = red[0] * (1.f/256.f);
  __syncthreads();
  float d = h - mu;
  red[tid] = d*d; __syncthreads();
  for (int off=128; off; off>>=1){ if (tid<off) red[tid]+=red[tid+off]; __syncthreads(); }
  float var = red[0] * (1.f/256.f);
  float yv = d * rsqrtf(var + 1e-5f) * ing[c] + inb[c];
  src[(size_t)tid*128 + b*16 + c] = yv;   // src[s][b][e], s=tid
}

// ---------------- attention with inline qkv (per b,h block; head dim = 2) ----------------
__launch_bounds__(256)
__global__ void k_attn2(const float* __restrict__ src, const float* __restrict__ aw,
                        const float* __restrict__ ab, float* __restrict__ obuf){
  int b = blockIdx.x >> 3, hh = blockIdx.x & 7;  // 64 blocks
  int t = threadIdx.x;                           // token s
  __shared__ float kk0[256], kk1[256], vv0[256], vv1[256];
  int tok = t*8 + b;
  float s[16];
  #pragma unroll
  for (int e=0;e<16;++e) s[e] = src[tok*16+e];
  float q0=ab[2*hh], q1=ab[2*hh+1];
  float k0=ab[16+2*hh], k1=ab[16+2*hh+1];
  float v0=ab[32+2*hh], v1=ab[32+2*hh+1];
  #pragma unroll
  for (int e=0;e<16;++e){
    float sv=s[e];
    q0 += sv*aw[(2*hh  )*16+e]; q1 += sv*aw[(2*hh+1)*16+e];
    k0 += sv*aw[(16+2*hh)*16+e]; k1 += sv*aw[(16+2*hh+1)*16+e];
    v0 += sv*aw[(32+2*hh)*16+e]; v1 += sv*aw[(32+2*hh+1)*16+e];
  }
  kk0[t]=k0; kk1[t]=k1; vv0[t]=v0; vv1[t]=v1;
  __syncthreads();
  const float sc = 0.70710678118654752f;  // 1/sqrt(2)
  float l=0.f, a0=0.f, a1=0.f;
  for (int u=0;u<256;++u){
    float p = __expf((q0*kk0[u]+q1*kk1[u])*sc);
    l+=p; a0+=p*vv0[u]; a1+=p*vv1[u];
  }
  float inv=1.f/l;
  obuf[tok*16 + 2*hh]   = a0*inv;
  obuf[tok*16 + 2*hh+1] = a1*inv;
}

// -------- per-token: oproj+ln1 + ffn+ln2 + level partial (2048 blocks x 64 thr) --------
__launch_bounds__(64)
__global__ void k_tok(const float* __restrict__ src, const float* __restrict__ obuf,
                      const float* __restrict__ ow, const float* __restrict__ ob,
                      const float* __restrict__ l1w, const float* __restrict__ l1b,
                      const float* __restrict__ l2w, const float* __restrict__ l2b,
                      const float* __restrict__ n1g, const float* __restrict__ n1b,
                      const float* __restrict__ n2g, const float* __restrict__ n2b,
                      const float* __restrict__ fw, float* __restrict__ gbacc){
  int tok = blockIdx.x, tid = threadIdx.x;
  int s = tok >> 3, b = tok & 7;
  __shared__ float shx[16], shy[16], h1[128];
  if (tid < 16){
    float t2 = ob[tid];
    #pragma unroll
    for (int f=0;f<16;++f) t2 += obuf[tok*16+f]*ow[tid*16+f];
    shx[tid] = src[tok*16+tid] + t2;
  }
  __syncthreads();
  if (tid < 16){
    float mu=0.f;
    #pragma unroll
    for (int e=0;e<16;++e) mu+=shx[e];
    mu*=(1.f/16.f);
    float var=0.f;
    #pragma unroll
    for (int e=0;e<16;++e){ float d=shx[e]-mu; var+=d*d; }
    var*=(1.f/16.f);
    shy[tid] = (shx[tid]-mu)*rsqrtf(var+1e-5f)*n1g[tid]+n1b[tid];
  }
  __syncthreads();
  for (int i=tid;i<128;i+=64){
    float u=l1b[i];
    #pragma unroll
    for (int e=0;e<16;++e) u += shy[e]*l1w[i*16+e];
    h1[i]=fmaxf(u,0.f);
  }
  __syncthreads();
  if (tid < 16){
    float x2=l2b[tid];
    for (int jj=0;jj<128;++jj) x2 += h1[jj]*l2w[tid*128+jj];
    shx[tid] = x2 + shy[tid];
  }
  __syncthreads();
  if (tid < 16){
    float mu=0.f;
    #pragma unroll
    for (int e=0;e<16;++e) mu+=shx[e];
    mu*=(1.f/16.f);
    float var=0.f;
    #pragma unroll
    for (int e=0;e<16;++e){ float d=shx[e]-mu; var+=d*d; }
    var*=(1.f/16.f);
    shy[tid]=(shx[tid]-mu)*rsqrtf(var+1e-5f)*n2g[tid]+n2b[tid];
  }
  __syncthreads();
  if (tid < 2){
    float p=0.f;
    #pragma unroll
    for (int c=0;c<16;++c) p += shy[c]*fw[(tid*16+c)*256 + s];
    atomicAdd(&gbacc[b*2+tid], p);
  }
}

// ============ fused conv chain + final elementwise ============
// LDS: vb 4232 + t1..t6 = 77800 B -> 2 WG/CU.
// launch_bounds arg-2 acts as min BLOCKS/CU: (512,2)->VGPR ~128 ok; (512,4)->64 spills.
__launch_bounds__(512,2)
__global__ void k_megaconv(const float* __restrict__ xg,
    const float* __restrict__ c1w, const float* __restrict__ c1b,
    const float* __restrict__ c2b, const float* __restrict__ c3b,
    const float* __restrict__ c4b, const float* __restrict__ c5b,
    const float* __restrict__ c6b, const float* __restrict__ c7b,
    const uint* __restrict__ wpk, const float* __restrict__ gbr,
    const float* __restrict__ fb,
    float* __restrict__ out)
{
  __shared__ __align__(16) ushort vb[46*46];
  __shared__ __align__(16) ushort t1[44*44*4];
  __shared__ __align__(16) ushort t2[42*42*4];
  __shared__ __align__(16) ushort t3[40*40*4];
  __shared__ __align__(16) ushort t4[38*38*4];
  __shared__ __align__(16) ushort t5[36*36*4];
  __shared__ __align__(16) ushort t6[34*34*4];
  int wg=blockIdx.x, b=wg>>8, t=wg&255, ty=t>>4, tx=t&15;
  int gy0=ty*32, gx0=tx*32, tid=threadIdx.x;
  const float* xp = xg + (size_t)b*3*PLANE;
  const bool interior = (ty>=1)&(ty<=14)&(tx>=1)&(tx<=14);

  // stage v window (origin gy0-7, gx0-7), 46x46, f16
  if (interior){
    for (int i=tid;i<46*46;i+=512){
      int rr=i/46, cc=i-rr*46;
      int off=(gy0-7+rr)*W + gx0-7+cc;
      float val=(xp[off]+xp[PLANE+off]+xp[2*PLANE+off])*(1.f/3.f);
      _Float16 hv=(_Float16)val;
      vb[i]=*(ushort*)&hv;
    }
  } else {
    for (int i=tid;i<46*46;i+=512){
      int rr=i/46, cc=i-rr*46;
      int gy=gy0-7+rr, gx=gx0-7+cc;
      float val=0.f;
      if (((unsigned)gy<512u)&((unsigned)gx<512u)){
        int off=gy*W+gx;
        val=(xp[off]+xp[PLANE+off]+xp[2*PLANE+off])*(1.f/3.f);
      }
      _Float16 hv=(_Float16)val;
      vb[i]=*(ushort*)&hv;
    }
  }
  __syncthreads();

  // c1: vb(46) -> t1(44), out origin gy0-6
  if (tid < 484){
    int qy=tid/22, qx=tid-qy*22, y0=2*qy, x0=2*qx;
    float a00[4],a01[4],a10[4],a11[4];
    #pragma unroll
    for (int co=0;co<4;++co){ float bv=c1b[co]; a00[co]=bv;a01[co]=bv;a10[co]=bv;a11[co]=bv; }
    accp4sc<46>(vb, c1w, y0, x0, a00,a01,a10,a11);
    if (interior){ STORE_CORE(t1, 44, true, true, true, true) }
    else         { STORE_TILE_B(t1, 44, -6) }
  }
  __syncthreads();

  // c2: t1(44) -> t2(42), out origin gy0-5
  if (tid < 441){
    int qy=tid/21, qx=tid-qy*21, y0=2*qy, x0=2*qx;
    float a00[4],a01[4],a10[4],a11[4];
    #pragma unroll
    for (int co=0;co<4;++co){ float bv=c2b[co]; a00[co]=bv;a01[co]=bv;a10[co]=bv;a11[co]=bv; }
    h2 win[4][4][2];
    LOADWIN_EVEN(win, t1, 44, y0, x0)
    LOADW(wl2, 0)
    DOTACC2(win, wl2)
    if (interior){ STORE_CORE(t2, 42, true, true, true, true) }
    else         { STORE_TILE_B(t2, 42, -5) }
  }
  __syncthreads();

  // c3: t2(42) -> t3(40), out origin gy0-4
  if (tid < 400){
    int qy=tid/20, qx=tid-qy*20, y0=2*qy, x0=2*qx;
    float a00[4],a01[4],a10[4],a11[4];
    #pragma unroll
    for (int co=0;co<4;++co){ float bv=c3b[co]; a00[co]=bv;a01[co]=bv;a10[co]=bv;a11[co]=bv; }
    h2 win[4][4][2];
    LOADWIN_EVEN(win, t2, 42, y0, x0)
    LOADW(wl3, 72)
    DOTACC2(win, wl3)
    if (interior){ STORE_CORE(t3, 40, true, true, true, true) }
    else         { STORE_TILE_B(t3, 40, -4) }
  }
  __syncthreads();

  // c4: t3(40) -> t4(38), out origin gy0-3
  if (tid < 361){
    int qy=tid/19, qx=tid-qy*19, y0=2*qy, x0=2*qx;
    float a00[4],a01[4],a10[4],a11[4];
    #pragma unroll
    for (int co=0;co<4;++co){ float bv=c4b[co]; a00[co]=bv;a01[co]=bv;a10[co]=bv;a11[co]=bv; }
    h2 win[4][4][2];
    LOADWIN_EVEN(win, t3, 40, y0, x0)
    LOADW(wl4, 144)
    DOTACC2(win, wl4)
    if (interior){ STORE_CORE(t4, 38, true, true, true, true) }
    else         { STORE_TILE_B(t4, 38, -3) }
  }
  __syncthreads();

  // c5: concat(t3@(+1,+1) odd, t4) -> t5(36), out origin gy0-2
  if (tid < 324){
    int qy=tid/18, qx=tid-qy*18, y0=2*qy, x0=2*qx;
    float a00[4],a01[4],a10[4],a11[4];
    #pragma unroll
    for (int co=0;co<4;++co){ float bv=c5b[co]; a00[co]=bv;a01[co]=bv;a10[co]=bv;a11[co]=bv; }
    {
      h2 win[4][4][2];
      LOADWIN_ODD(win, t3, 40, y0+1, x0+1)
      LOADW(wlA, 216)
      DOTACC2(win, wlA)
    }
    {
      h2 win[4][4][2];
      LOADWIN_EVEN(win, t4, 38, y0, x0)
      LOADW(wlB, 288)
      DOTACC2(win, wlB)
    }
    if (interior){ STORE_CORE(t5, 36, true, true, true, true) }
    else         { STORE_TILE_B(t5, 36, -2) }
  }
  __syncthreads();

  // c6: concat(t2@(+3,+3) odd, t5) -> t6(34), out origin gy0-1
  if (tid < 289){
    int qy=tid/17, qx=tid-qy*17, y0=2*qy, x0=2*qx;
    float a00[4],a01[4],a10[4],a11[4];
    #pragma unroll
    for (int co=0;co<4;++co){ float bv=c6b[co]; a00[co]=bv;a01[co]=bv;a10[co]=bv;a11[co]=bv; }
    {
      h2 win[4][4][2];
      LOADWIN_ODD(win, t2, 42, y0+3, x0+3)
      LOADW(wlA, 360)
      DOTACC2(win, wlA)
    }
    {
      h2 win[4][4][2];
      LOADWIN_EVEN(win, t5, 36, y0, x0)
      LOADW(wlB, 432)
      DOTACC2(win, wlB)
    }
    if (interior){ STORE_CORE(t6, 34, true, true, true, true) }
    else         { STORE_TILE_B(t6, 34, -1) }
  }
  __syncthreads();

  // c7: concat(t1@(+5,+5) odd, t6) -> sigmoid -> v_r + fused final elementwise
  if (tid < 256){
    int qy=tid>>4, qx=tid&15, y0=2*qy, x0=2*qx;
    float bv=c7b[0];
    float s00=bv, s01=bv, s10=bv, s11=bv;
    uint wl7[36];
    #pragma unroll
    for (int i_=0;i_<36;++i_) wl7[i_]=wpk[504+i_];
    {
      h2 win[4][4][2];
      LOADWIN_ODD(win, t1, 44, y0+5, x0+5)
      DOTACC1(win, wl7, 0)
    }
    {
      h2 win[4][4][2];
      LOADWIN_EVEN(win, t6, 34, y0, x0)
      DOTACC1(win, wl7, 2)
    }
    s00 = 1.f/(1.f+__expf(-s00)); s01 = 1.f/(1.f+__expf(-s01));
    s10 = 1.f/(1.f+__expf(-s10)); s11 = 1.f/(1.f+__expf(-s11));
    float* vo = out + 6291456 + (size_t)b*PLANE;
    *(float2*)&vo[(gy0+y0  )*512 + gx0+x0] = make_float2(s00,s01);
    *(float2*)&vo[(gy0+y0+1)*512 + gx0+x0] = make_float2(s10,s11);

    // level scalars from raw accumulated sums
    float lev0 = 1.f/(1.f+__expf(-(gbr[b*2+0]+fb[0])));
    float lev1 = 1.f/(1.f+__expf(-(gbr[b*2+1]+fb[1])));
    float gg  = 0.1f*lev0+0.2f;
    float bcf = 0.04f*lev1+0.06f;
    float lg = log2f(gg);
    #pragma unroll
    for (int py=0; py<2; ++py){
      int gy=gy0+y0+py, gx=gx0+x0;
      int off=gy*W+gx;
      float2 R = *(const float2*)&xp[off];
      float2 G = *(const float2*)&xp[PLANE+off];
      float2 B = *(const float2*)&xp[2*PLANE+off];
      float vr0 = py? s10:s00, vr1 = py? s11:s01;
      float2 er,eg,eb,tr,tg,tb;
#define COMP1(RF,GF,BF,VRF,ER,EG,EB,TR,TG,TB) { \
      float vv=(RF+GF+BF)*(1.f/3.f); \
      float v0c=fminf(fmaxf(vv,1e-6f),0.999999f); \
      float r0=exp2f((VRF)*lg); \
      float ev0=exp2f(r0*log2f(v0c)); \
      float dd=bcf-vv; \
      float L=400.f*dd*dd*dd; \
      L=(L<1e-5f)?1e-6f:L; \
      float fac=(ev0-L)/(vv+1e-6f); \
      ER=RF*fac; EG=GF*fac; EB=BF*fac; \
      bool z=vv>0.04f; \
      TR=z?0.f:ER; TG=z?0.f:EG; TB=z?0.f:EB; }
      COMP1(R.x,G.x,B.x,vr0, er.x,eg.x,eb.x, tr.x,tg.x,tb.x)
      COMP1(R.y,G.y,B.y,vr1, er.y,eg.y,eb.y, tr.y,tg.y,tb.y)
#undef COMP1
      *(float2*)&out[(size_t)(b*3+0)*PLANE + off] = er;
      *(float2*)&out[(size_t)(b*3+1)*PLANE + off] = eg;
      *(float2*)&out[(size_t)(b*3+2)*PLANE + off] = eb;
      *(float2*)&out[8388608 + (size_t)(b*3+0)*PLANE + off] = tr;
      *(float2*)&out[8388608 + (size_t)(b*3+1)*PLANE + off] = tg;
      *(float2*)&out[8388608 + (size_t)(b*3+2)*PLANE + off] = tb;
    }
  }
}

extern "C" void kernel_launch(void* const* d_in, const int* in_sizes, int n_in,
                              void* d_out, int out_size, void* d_ws, size_t ws_size,
                              hipStream_t stream) {
  const float* x    = (const float*)d_in[0];
  const float* c1w  = (const float*)d_in[1];  const float* c1b = (const float*)d_in[2];
  const float* c2w  = (const float*)d_in[3];  const float* c2b = (const float*)d_in[4];
  const float* c3w  = (const float*)d_in[5];  const float* c3b = (const float*)d_in[6];
  const float* c4w  = (const float*)d_in[7];  const float* c4b = (const float*)d_in[8];
  const float* c5w  = (const float*)d_in[9];  const float* c5b = (const float*)d_in[10];
  const float* c6w  = (const float*)d_in[11]; const float* c6b = (const float*)d_in[12];
  const float* c7w  = (const float*)d_in[13]; const float* c7b = (const float*)d_in[14];
  const float* mw   = (const float*)d_in[15]; const float* mb  = (const float*)d_in[16];
  const float* ing  = (const float*)d_in[17]; const float* inb = (const float*)d_in[18];
  const float* aw   = (const float*)d_in[19]; const float* ab  = (const float*)d_in[20];
  const float* ow   = (const float*)d_in[21]; const float* ob  = (const float*)d_in[22];
  const float* l1w  = (const float*)d_in[23]; const float* l1b = (const float*)d_in[24];
  const float* l2w  = (const float*)d_in[25]; const float* l2b = (const float*)d_in[26];
  const float* n1g  = (const float*)d_in[27]; const float* n1b = (const float*)d_in[28];
  const float* n2g  = (const float*)d_in[29]; const float* n2b = (const float*)d_in[30];
  const float* fw   = (const float*)d_in[31]; const float* fb  = (const float*)d_in[32];

  uint* wpk = (uint*)d_ws;             // 540 uints
  float* gbacc = (float*)(wpk + 1024); // 16 floats (raw level sums)
  float* src  = gbacc + 16;            // 32,768
  float* obuf = src + 32768;           // 32,768
  float* out  = (float*)d_out;

  k_mnorm<<<129,256,0,stream>>>(x, mw, mb, ing, inb, src,
                                c2w, c3w, c4w, c5w, c6w, c7w, wpk, gbacc);
  k_attn2<<<64,256,0,stream>>>(src, aw, ab, obuf);
  k_tok<<<2048,64,0,stream>>>(src, obuf, ow, ob, l1w, l1b, l2w, l2b,
                              n1g, n1b, n2g, n2b, fw, gbacc);
  k_megaconv<<<2048,512,0,stream>>>(x, c1w, c1b, c2b, c3b, c4b, c5b, c6b, c7b,
                                    wpk, gbacc, fb, out);
}